// Round 1
// baseline (1889.565 us; speedup 1.0000x reference)
//
#include <hip/hip_runtime.h>
#include <stdint.h>

#define T_STEPS 512
#define BATCH   128
#define N_IN    256
#define N_H     1024
#define N_OUT   32

// ---------------- Kernel A: compact spike indices per (t,b) row ----------------
// Output: pairs[row][32] u32 words, each = idx_even | idx_odd<<16 (u16 indices,
// sentinel 256 for padding); cnts[row] = active count (<=64).
__global__ __launch_bounds__(256) void k_prep(const float* __restrict__ spikes,
                                              uint32_t* __restrict__ pairs,
                                              uint32_t* __restrict__ cnts) {
    const int row = blockIdx.x;            // t*BATCH + b
    const int tid = threadIdx.x;
    float s = spikes[(size_t)row * N_IN + tid];
    bool act = s > 0.5f;                   // spikes are exactly 0.0/1.0
    unsigned long long m = __ballot(act);
    __shared__ uint16_t list[64];
    __shared__ uint32_t wcnt[4];
    if (tid < 64) list[tid] = 256;         // sentinel -> LDS zero row in k_lif
    const int wave = tid >> 6, lane = tid & 63;
    if (lane == 0) wcnt[wave] = (uint32_t)__popcll(m);
    __syncthreads();
    uint32_t off = 0;
    for (int w = 0; w < wave; ++w) off += wcnt[w];
    uint32_t total = wcnt[0] + wcnt[1] + wcnt[2] + wcnt[3];
    if (act) {
        uint32_t pos = off + (uint32_t)__popcll(m & ((1ull << lane) - 1ull));
        if (pos < 64) list[pos] = (uint16_t)tid;   // index i = tid, ascending order
    }
    __syncthreads();
    if (tid < 32) {
        uint32_t w = (uint32_t)list[2 * tid] | ((uint32_t)list[2 * tid + 1] << 16);
        pairs[(size_t)row * 32 + tid] = w;
    }
    if (tid == 0) cnts[row] = total < 64u ? total : 64u;
}

// ---------------- Kernel T: transpose w_h[h][i] -> w_t[i][h] ----------------
__global__ __launch_bounds__(256) void k_tr(const float* __restrict__ w_h,
                                            float* __restrict__ w_t) {
    int gid = blockIdx.x * 256 + threadIdx.x;   // 262144 elements
    int h = gid >> 8, i = gid & 255;
    w_t[(size_t)i * N_H + h] = w_h[gid];
}

// ---------------- Kernel 12: fused sparse synapse + LIF scan ----------------
// Grid: 128 b * 8 h-tiles. Block 256 thr; lane pair (2h,2h+1) both own h=tid>>1,
// parity splits actives by list position. Dynamic LDS: w tile [257][128] fp32
// (row 256 = zeros for sentinel). No barrier inside the t-loop.
__global__ __launch_bounds__(256) void k_lif(const uint32_t* __restrict__ pairs,
                                             const uint32_t* __restrict__ cnts,
                                             const float* __restrict__ w_t,
                                             uint32_t* __restrict__ zmask) {
    extern __shared__ __align__(16) float wl[];   // (256+1)*128 floats
    const int b   = blockIdx.x >> 3;
    const int ht  = blockIdx.x & 7;
    const int h0  = ht * 128;
    const int tid = threadIdx.x;

    // Fill LDS tile: coalesced float4 reads from w_t (conflict-free LDS writes)
    #pragma unroll
    for (int k = 0; k < 32; ++k) {
        int it  = k * 256 + tid;          // 8192 float4 slots
        int i   = it >> 5;
        int hh4 = (it & 31) << 2;
        *(float4*)(wl + i * 128 + hh4) =
            *(const float4*)(w_t + (size_t)i * N_H + h0 + hh4);
    }
    if (tid < 128) wl[256 * 128 + tid] = 0.0f;    // sentinel row
    __syncthreads();

    const int lane_h      = tid >> 1;             // 0..127
    const uint32_t vshift = (uint32_t)(tid & 1) << 4;  // 0 or 16
    const int zbase       = ht * 4 + (tid >> 6);

    float v = 0.0f, cur = 0.0f;

    // prefetch row for t=0
    uint32_t cnt_n = cnts[b];
    const uint4* wp0 = (const uint4*)(pairs + (size_t)b * 32);
    uint4 A_n = wp0[0], B_n = wp0[1], C_n = wp0[2], D_n = wp0[3];

    for (int t = 0; t < T_STEPS; ++t) {
        uint32_t cnt = cnt_n;
        uint4 A = A_n, Bv = B_n, C = C_n, D = D_n;

        int rn   = (t + 1 < T_STEPS) ? (t + 1) : t;
        int rown = rn * BATCH + b;
        cnt_n = cnts[rown];
        const uint4* wpn = (const uint4*)(pairs + (size_t)rown * 32);
        A_n = wpn[0]; B_n = wpn[1]; C_n = wpn[2]; D_n = wpn[3];

        float c = 0.0f;
        #define GR(g, w0, w1) if (cnt > 4u * g) {              \
            uint32_t ia = ((w0) >> vshift) & 0xFFFFu;          \
            uint32_t ib = ((w1) >> vshift) & 0xFFFFu;          \
            c += wl[ia * 128 + lane_h];                        \
            c += wl[ib * 128 + lane_h]; }
        GR(0, A.x, A.y)   GR(1, A.z, A.w)
        GR(2, Bv.x, Bv.y) GR(3, Bv.z, Bv.w)
        GR(4, C.x, C.y)   GR(5, C.z, C.w)
        GR(6, D.x, D.y)   GR(7, D.z, D.w)
        if (cnt > 32u) {  // rare (~8%) tail
            const uint4* wpc = (const uint4*)(pairs + (size_t)(t * BATCH + b) * 32);
            uint4 E = wpc[4], F = wpc[5], G = wpc[6], H = wpc[7];
            GR(8, E.x, E.y)   GR(9, E.z, E.w)
            GR(10, F.x, F.y)  GR(11, F.z, F.w)
            GR(12, G.x, G.y)  GR(13, G.z, G.w)
            GR(14, H.x, H.y)  GR(15, H.z, H.w)
        }
        #undef GR

        c += __shfl_xor(c, 1);            // combine parity halves (both lanes get full c)
        cur = cur * 0.875f + c;           // i = i*(1-DI) + c_t
        v  += 0.125f * (cur - v);         // v = v + DV*(i - v)
        bool sp = v > 1.0f;               // z = H(v - 1)
        unsigned long long bal = __ballot(sp);
        if (sp) v = 0.0f;                 // reset

        // compress duplicated pair bits (even-bit extract) -> 32 h bits per wave
        unsigned long long x = bal & 0x5555555555555555ull;
        x = (x | (x >> 1))  & 0x3333333333333333ull;
        x = (x | (x >> 2))  & 0x0F0F0F0F0F0F0F0Full;
        x = (x | (x >> 4))  & 0x00FF00FF00FF00FFull;
        x = (x | (x >> 8))  & 0x0000FFFF0000FFFFull;
        x = (x | (x >> 16));
        if ((tid & 63) == 0)
            zmask[(size_t)(t * BATCH + b) * 32 + zbase] = (uint32_t)x;
    }
}

// ---------------- Kernel 34: sparse output synapse + LI scan ----------------
// Grid: 128 b * 2 h-halves. LI is linear -> each half runs its own LI on the
// partial current and atomicAdd's into out (2 commutative adds = deterministic).
__global__ __launch_bounds__(512) void k_li(const uint32_t* __restrict__ zmask,
                                            const float* __restrict__ w_o,
                                            float* __restrict__ out) {
    extern __shared__ __align__(16) float wo[];   // [32][513] floats (padded)
    const int b = blockIdx.x >> 1, half = blockIdx.x & 1;
    const int tid = threadIdx.x;
    for (int lin = tid; lin < 32 * 512; lin += 512) {
        int o = lin >> 9, h = lin & 511;
        wo[o * 513 + h] = w_o[(size_t)o * N_H + half * 512 + h];
    }
    __syncthreads();

    const int o = tid >> 4, ch = tid & 15;        // 32 outputs x 16 h-chunks
    const int wbase = half * 16 + ch;             // z word index
    const float* wrow = wo + o * 513 + ch * 32;

    float v = 0.0f, cur = 0.0f;
    uint32_t m_n = zmask[(size_t)b * 32 + wbase];
    for (int t = 0; t < T_STEPS; ++t) {
        uint32_t m = m_n;
        int tn = (t + 1 < T_STEPS) ? t + 1 : t;
        m_n = zmask[(size_t)(tn * BATCH + b) * 32 + wbase];

        float c = 0.0f;
        while (m) {
            int j = __builtin_ctz(m);
            m &= m - 1;
            c += wrow[j];
        }
        c += __shfl_xor(c, 1);
        c += __shfl_xor(c, 2);
        c += __shfl_xor(c, 4);
        c += __shfl_xor(c, 8);            // ch==0 lanes now hold full half-sum

        cur = cur * 0.875f + c;
        v  += 0.125f * (cur - v);
        if (ch == 0)
            atomicAdd(out + (size_t)(t * BATCH + b) * 32 + o, v);
    }
}

// ---------------- launch ----------------
extern "C" void kernel_launch(void* const* d_in, const int* in_sizes, int n_in,
                              void* d_out, int out_size, void* d_ws, size_t ws_size,
                              hipStream_t stream) {
    const float* spikes = (const float*)d_in[0];
    const float* w_h    = (const float*)d_in[1];
    const float* w_o    = (const float*)d_in[2];
    float* out = (float*)d_out;

    char* ws = (char*)d_ws;
    uint32_t* pairs = (uint32_t*)(ws);                 // 8,388,608 B
    uint32_t* cnts  = (uint32_t*)(ws + 8388608);       //   262,144 B
    float*    w_t   = (float*)   (ws + 8650752);       // 1,048,576 B
    uint32_t* zmask = (uint32_t*)(ws + 9699328);       // 8,388,608 B  (end 18,087,936)

    const int lds12 = 257 * 128 * 4;   // 131,584 B
    const int lds34 = 32 * 513 * 4;    //  65,664 B
    hipFuncSetAttribute((const void*)k_lif, hipFuncAttributeMaxDynamicSharedMemorySize, lds12);
    hipFuncSetAttribute((const void*)k_li,  hipFuncAttributeMaxDynamicSharedMemorySize, lds34);

    hipMemsetAsync(d_out, 0, (size_t)out_size * sizeof(float), stream);
    k_prep<<<T_STEPS * BATCH, 256, 0, stream>>>(spikes, pairs, cnts);
    k_tr<<<(N_H * N_IN) / 256, 256, 0, stream>>>(w_h, w_t);
    k_lif<<<BATCH * 8, 256, lds12, stream>>>(pairs, cnts, w_t, zmask);
    k_li<<<BATCH * 2, 512, lds34, stream>>>(zmask, w_o, out);
}

// Round 3
// 977.807 us; speedup vs baseline: 1.9325x; 1.9325x over previous
//
#include <hip/hip_runtime.h>
#include <stdint.h>

#define T_STEPS 512
#define BATCH   128
#define N_IN    256
#define N_H     1024
#define N_OUT   32

// ---------------- Kernel A: compact spike indices per (t,b) row ----------------
// pairs[row][32] u32 words, each = idx_even | idx_odd<<16 (sentinel 256 -> zero
// row in the LDS weight tile); cnts[row] = active count (<=64).
__global__ __launch_bounds__(256) void k_prep(const float* __restrict__ spikes,
                                              uint32_t* __restrict__ pairs,
                                              uint32_t* __restrict__ cnts) {
    const int row = blockIdx.x;            // t*BATCH + b
    const int tid = threadIdx.x;
    float s = spikes[(size_t)row * N_IN + tid];
    bool act = s > 0.5f;                   // spikes are exactly 0.0/1.0
    unsigned long long m = __ballot(act);
    __shared__ uint16_t list[64];
    __shared__ uint32_t wcnt[4];
    if (tid < 64) list[tid] = 256;         // sentinel
    const int wave = tid >> 6, lane = tid & 63;
    if (lane == 0) wcnt[wave] = (uint32_t)__popcll(m);
    __syncthreads();
    uint32_t off = 0;
    for (int w = 0; w < wave; ++w) off += wcnt[w];
    uint32_t total = wcnt[0] + wcnt[1] + wcnt[2] + wcnt[3];
    if (act) {
        uint32_t pos = off + (uint32_t)__popcll(m & ((1ull << lane) - 1ull));
        if (pos < 64) list[pos] = (uint16_t)tid;   // ascending input index order
    }
    __syncthreads();
    if (tid < 32) {
        uint32_t w = (uint32_t)list[2 * tid] | ((uint32_t)list[2 * tid + 1] << 16);
        pairs[(size_t)row * 32 + tid] = w;
    }
    if (tid == 0) cnts[row] = total < 64u ? total : 64u;
}

// ---------------- Kernel T: transpose w_h[h][i] -> w_t[i][h] ----------------
__global__ __launch_bounds__(256) void k_tr(const float* __restrict__ w_h,
                                            float* __restrict__ w_t) {
    int gid = blockIdx.x * 256 + threadIdx.x;   // 262144 elements
    int h = gid >> 8, i = gid & 255;
    w_t[(size_t)i * N_H + h] = w_h[gid];
}

// ---------------- Kernel 12: fused sparse synapse + LIF scan ----------------
// Grid: 32 b-groups * 8 h-tiles (128 h each) = 256 blocks; block = 256 thr =
// 4 waves = 4 b sharing one LDS weight tile wl[257][128] (row 256 = zeros).
// Wave lane l: h-quad q = l&31 (h = 4q..4q+3, ds_read_b128), parity p = l>>5
// splits the active list by position LSB. No barrier in the t-loop.
// __launch_bounds__(256,1): 1 block/CU (LDS-bound) -> big VGPR budget, no
// scratch spills (round-1 killer: 36 VGPRs + 33 GB spill traffic).
__global__ __launch_bounds__(256, 1) void k_lif(const uint32_t* __restrict__ pairs,
                                                const uint32_t* __restrict__ cnts,
                                                const float* __restrict__ w_t,
                                                uint32_t* __restrict__ zmask) {
    extern __shared__ __align__(16) float wl[];   // 257*128 floats = 131,584 B
    const int bg = blockIdx.x >> 3, tile = blockIdx.x & 7;
    const int h0 = tile * 128, tid = threadIdx.x;

    #pragma unroll 8
    for (int k = 0; k < 32; ++k) {                // 256 rows x 32 float4
        int idx = (k << 8) + tid;
        int i = idx >> 5, c4 = (idx & 31) << 2;
        *(float4*)(wl + i * 128 + c4) =
            *(const float4*)(w_t + (size_t)i * N_H + h0 + c4);
    }
    if (tid < 128) wl[256 * 128 + tid] = 0.0f;    // sentinel row
    __syncthreads();

    const int b = (bg << 2) + (tid >> 6);         // one b per wave
    const int l = tid & 63;
    const int q4 = (l & 31) << 2;                 // float offset of h-quad
    const uint32_t vshift = (uint32_t)((l >> 5) << 4);  // parity: 0 or 16

    uint32_t cnt;
    uint4 W0, W1, W2, W3, W4, W5, W6, W7;         // full 128 B index row

    auto load_idx = [&](int row) {
        const uint4* wp = (const uint4*)(pairs + (size_t)row * 32);
        cnt = cnts[row];
        W0 = wp[0]; W1 = wp[1]; W2 = wp[2]; W3 = wp[3];
        W4 = wp[4]; W5 = wp[5]; W6 = wp[6]; W7 = wp[7];
    };
    auto gather = [&](float& g0, float& g1, float& g2, float& g3) {
        uint32_t cs = __builtin_amdgcn_readfirstlane(cnt);  // uniform guards
        g0 = g1 = g2 = g3 = 0.0f;
#define GW(JW, WRD) if (cs > (2u*(JW))) { \
        uint32_t ia = ((WRD) >> vshift) & 0xFFFFu; \
        const float4 t4 = *(const float4*)(wl + ia * 128 + q4); \
        g0 += t4.x; g1 += t4.y; g2 += t4.z; g3 += t4.w; }
        GW(0,W0.x)  GW(1,W0.y)  GW(2,W0.z)  GW(3,W0.w)
        GW(4,W1.x)  GW(5,W1.y)  GW(6,W1.z)  GW(7,W1.w)
        GW(8,W2.x)  GW(9,W2.y)  GW(10,W2.z) GW(11,W2.w)
        GW(12,W3.x) GW(13,W3.y) GW(14,W3.z) GW(15,W3.w)
        GW(16,W4.x) GW(17,W4.y) GW(18,W4.z) GW(19,W4.w)
        GW(20,W5.x) GW(21,W5.y) GW(22,W5.z) GW(23,W5.w)
        GW(24,W6.x) GW(25,W6.y) GW(26,W6.z) GW(27,W6.w)
        GW(28,W7.x) GW(29,W7.y) GW(30,W7.z) GW(31,W7.w)
#undef GW
    };

    float v0=0,v1=0,v2=0,v3=0, s0=0,s1=0,s2=0,s3=0;
    float c0,c1,c2,c3;
    load_idx(b);                         // idx(0)
    gather(c0, c1, c2, c3);              // currents for t=0
    load_idx(BATCH + b);                 // idx(1)

    uint4* zp = (uint4*)(zmask + (size_t)b * 32 + (tile << 2));
    const int zstride = (BATCH * 32) >> 2;

    for (int t = 0; t < T_STEPS; ++t) {
        // combine parity halves (exact commutative add, both lanes get full c)
        c0 += __shfl_xor(c0, 32);
        c1 += __shfl_xor(c1, 32);
        c2 += __shfl_xor(c2, 32);
        c3 += __shfl_xor(c3, 32);

        float n0, n1, n2, n3;
        gather(n0, n1, n2, n3);          // software-pipelined gather for t+1

        int rn = t + 2; if (rn > T_STEPS - 1) rn = T_STEPS - 1;
        load_idx(rn * BATCH + b);        // prefetch idx(t+2)

        // LIF (fma forms locked to round-1's passing arithmetic)
        s0 = __builtin_fmaf(s0, 0.875f, c0);
        s1 = __builtin_fmaf(s1, 0.875f, c1);
        s2 = __builtin_fmaf(s2, 0.875f, c2);
        s3 = __builtin_fmaf(s3, 0.875f, c3);
        v0 = __builtin_fmaf(0.125f, s0 - v0, v0);
        v1 = __builtin_fmaf(0.125f, s1 - v1, v1);
        v2 = __builtin_fmaf(0.125f, s2 - v2, v2);
        v3 = __builtin_fmaf(0.125f, s3 - v3, v3);

        unsigned long long m0 = __ballot(v0 > 1.0f);
        unsigned long long m1 = __ballot(v1 > 1.0f);
        unsigned long long m2 = __ballot(v2 > 1.0f);
        unsigned long long m3 = __ballot(v3 > 1.0f);
        if (v0 > 1.0f) v0 = 0.0f;
        if (v1 > 1.0f) v1 = 0.0f;
        if (v2 > 1.0f) v2 = 0.0f;
        if (v3 > 1.0f) v3 = 0.0f;
        // word (tile*4+k), bit q  <->  h = tile*128 + 4q + k
        if (l == 0)
            *zp = make_uint4((uint32_t)m0, (uint32_t)m1, (uint32_t)m2, (uint32_t)m3);
        zp += zstride;
        c0 = n0; c1 = n1; c2 = n2; c3 = n3;
    }
}

// ---------------- Kernel 34: sparse output synapse + LI scan ----------------
// Grid: 128 b * 2 h-halves, 512 thr. Lane = (o, ch): o = tid>>4, ch = tid&15
// scans one zmask u32 word per t. LI is linear -> each lane runs LI on its
// partial current; 3-level shfl tree + 4 atomicAdds per (t,b,o).
__global__ __launch_bounds__(512, 1) void k_li(const uint32_t* __restrict__ zmask,
                                               const float* __restrict__ w_o,
                                               float* __restrict__ out) {
    extern __shared__ __align__(16) float wo[];   // 32 * 521 floats = 66,688 B
    const int b = blockIdx.x >> 1, half = blockIdx.x & 1;
    const int tid = threadIdx.x;
    // stage w_o permuted to match zmask bit mapping: entry (o, ch, j) = w_o[o][h]
    for (int lin = tid; lin < 32 * 512; lin += 512) {
        int o = lin >> 9, idx = lin & 511;
        int ch = idx >> 5, j = idx & 31;
        int word = half * 16 + ch;
        int h = ((word >> 2) << 7) + (j << 2) + (word & 3);
        wo[o * 521 + idx] = w_o[(size_t)o * N_H + h];
    }
    __syncthreads();

    const int o = tid >> 4, ch = tid & 15;
    const float* wrow = wo + o * 521 + (ch << 5);
    const int woff = half * 16 + ch;

    float v = 0.0f, s = 0.0f;
    uint32_t m_n = zmask[(size_t)b * 32 + woff];
    for (int t = 0; t < T_STEPS; ++t) {
        uint32_t m = m_n;
        int tn = (t + 1 < T_STEPS) ? t + 1 : t;
        m_n = zmask[(size_t)(tn * BATCH + b) * 32 + woff];

        float c = 0.0f;
        while (m) { int j = __builtin_ctz(m); m &= m - 1; c += wrow[j]; }

        s = __builtin_fmaf(s, 0.875f, c);
        v = __builtin_fmaf(0.125f, s - v, v);

        float r = v + __shfl_xor(v, 1);
        r += __shfl_xor(r, 2);
        r += __shfl_xor(r, 4);
        if ((ch & 7) == 0)
            atomicAdd(out + (size_t)(t * BATCH + b) * 32 + o, r);
    }
}

// ---------------- launch ----------------
extern "C" void kernel_launch(void* const* d_in, const int* in_sizes, int n_in,
                              void* d_out, int out_size, void* d_ws, size_t ws_size,
                              hipStream_t stream) {
    const float* spikes = (const float*)d_in[0];
    const float* w_h    = (const float*)d_in[1];
    const float* w_o    = (const float*)d_in[2];
    float* out = (float*)d_out;

    char* ws = (char*)d_ws;
    uint32_t* pairs = (uint32_t*)(ws);                 // 8,388,608 B
    uint32_t* cnts  = (uint32_t*)(ws + 8388608);       //   262,144 B
    float*    w_t   = (float*)   (ws + 8650752);       // 1,048,576 B
    uint32_t* zmask = (uint32_t*)(ws + 9699328);       // 8,388,608 B

    const int lds12 = 257 * 128 * 4;   // 131,584 B
    const int lds34 = 32 * 521 * 4;    //  66,688 B
    hipFuncSetAttribute((const void*)k_lif, hipFuncAttributeMaxDynamicSharedMemorySize, lds12);
    hipFuncSetAttribute((const void*)k_li,  hipFuncAttributeMaxDynamicSharedMemorySize, lds34);

    hipMemsetAsync(d_out, 0, (size_t)out_size * sizeof(float), stream);
    k_prep<<<T_STEPS * BATCH, 256, 0, stream>>>(spikes, pairs, cnts);
    k_tr<<<(N_H * N_IN) / 256, 256, 0, stream>>>(w_h, w_t);
    k_lif<<<256, 256, lds12, stream>>>(pairs, cnts, w_t, zmask);
    k_li<<<BATCH * 2, 512, lds34, stream>>>(zmask, w_o, out);
}

// Round 4
// 975.023 us; speedup vs baseline: 1.9380x; 1.0029x over previous
//
#include <hip/hip_runtime.h>
#include <stdint.h>

#define T_STEPS 512
#define BATCH   128
#define N_IN    256
#define N_H     1024
#define N_OUT   32

// ---------------- Kernel A: compact spike indices, 16 rows per block ----------------
// pairs[row][32] u32 words, each = idx_even | idx_odd<<16 (sentinel 256 -> zero
// row in the LDS weight tile); cnts[row] = active count (<=64).
// 16 rows/block: grid 65536 -> 4096 (round-3 dispatch-overhead fix).
__global__ __launch_bounds__(256) void k_prep(const float* __restrict__ spikes,
                                              uint32_t* __restrict__ pairs,
                                              uint32_t* __restrict__ cnts) {
    __shared__ uint16_t list[64];
    __shared__ uint32_t wcnt[4];
    const int tid = threadIdx.x;
    const int wave = tid >> 6, lane = tid & 63;
    for (int r = 0; r < 16; ++r) {
        const int row = blockIdx.x * 16 + r;       // t*BATCH + b
        float s = spikes[(size_t)row * N_IN + tid];
        bool act = s > 0.5f;                       // spikes are exactly 0.0/1.0
        unsigned long long m = __ballot(act);
        if (tid < 64) list[tid] = 256;             // sentinel
        if (lane == 0) wcnt[wave] = (uint32_t)__popcll(m);
        __syncthreads();
        uint32_t off = 0;
        for (int w = 0; w < wave; ++w) off += wcnt[w];
        uint32_t total = wcnt[0] + wcnt[1] + wcnt[2] + wcnt[3];
        if (act) {
            uint32_t pos = off + (uint32_t)__popcll(m & ((1ull << lane) - 1ull));
            if (pos < 64) list[pos] = (uint16_t)tid;   // ascending input index order
        }
        __syncthreads();
        if (tid < 32) {
            uint32_t w = (uint32_t)list[2 * tid] | ((uint32_t)list[2 * tid + 1] << 16);
            pairs[(size_t)row * 32 + tid] = w;
        }
        if (tid == 0) cnts[row] = total < 64u ? total : 64u;
        __syncthreads();                           // protect list/wcnt reuse next iter
    }
}

// ---------------- Kernel T: transpose w_h[h][i] -> w_t[i][h] ----------------
__global__ __launch_bounds__(256) void k_tr(const float* __restrict__ w_h,
                                            float* __restrict__ w_t) {
    int gid = blockIdx.x * 256 + threadIdx.x;   // 262144 elements
    int h = gid >> 8, i = gid & 255;
    w_t[(size_t)i * N_H + h] = w_h[gid];
}

// ---------------- Kernel 12: fused sparse synapse + LIF scan ----------------
// Round-4 geometry: wave owns (b, 64 h). Lane l: h-duo d = l&31 (h = 2d,2d+1 via
// ds_read_b64), parity p = l>>5 splits active list by position LSB (same split,
// same per-h accumulation order as round 3 -> bit-identical spikes).
// Grid: 32 b-groups x 16 h-tiles = 512 blocks, 4 waves (4 b) per block sharing
// one LDS tile wl[257][64] (row 256 = zeros). 65.8 KB LDS -> 2 blocks/CU ->
// 8 waves/CU = 2 waves/SIMD (round 3 had 1/SIMD: zero TLP, latency-bound).
__global__ __launch_bounds__(256) void k_lif(const uint32_t* __restrict__ pairs,
                                             const uint32_t* __restrict__ cnts,
                                             const float* __restrict__ w_t,
                                             uint32_t* __restrict__ zmask) {
    extern __shared__ __align__(16) float wl[];   // 257*64 floats = 65,792 B
    const int bg = blockIdx.x >> 4, tile = blockIdx.x & 15;
    const int h0 = tile * 64, tid = threadIdx.x;

    #pragma unroll 8
    for (int k = 0; k < 16; ++k) {                // 256 rows x 16 float4
        int idx = (k << 8) + tid;                 // 0..4095
        int i = idx >> 4, c4 = (idx & 15) << 2;
        *(float4*)(wl + i * 64 + c4) =
            *(const float4*)(w_t + (size_t)i * N_H + h0 + c4);
    }
    if (tid < 64) wl[256 * 64 + tid] = 0.0f;      // sentinel row
    __syncthreads();

    const int b = (bg << 2) + (tid >> 6);         // one b per wave
    const int l = tid & 63;
    const int duo2 = (l & 31) << 1;               // float offset of h-duo
    const uint32_t vshift = (uint32_t)((l >> 5) << 4);  // parity: 0 or 16

    uint32_t cnt;
    uint4 W0, W1, W2, W3, W4, W5, W6, W7;         // full 128 B index row

    auto load_idx = [&](int row) {
        const uint4* wp = (const uint4*)(pairs + (size_t)row * 32);
        cnt = cnts[row];
        W0 = wp[0]; W1 = wp[1]; W2 = wp[2]; W3 = wp[3];
        W4 = wp[4]; W5 = wp[5]; W6 = wp[6]; W7 = wp[7];
    };
    auto gather = [&](float& g0, float& g1) {
        uint32_t cs = __builtin_amdgcn_readfirstlane(cnt);  // uniform guards
        g0 = g1 = 0.0f;
#define GW(JW, WRD) if (cs > (2u*(JW))) { \
        uint32_t ia = ((WRD) >> vshift) & 0xFFFFu; \
        const float2 t2 = *(const float2*)(wl + ia * 64 + duo2); \
        g0 += t2.x; g1 += t2.y; }
        GW(0,W0.x)  GW(1,W0.y)  GW(2,W0.z)  GW(3,W0.w)
        GW(4,W1.x)  GW(5,W1.y)  GW(6,W1.z)  GW(7,W1.w)
        GW(8,W2.x)  GW(9,W2.y)  GW(10,W2.z) GW(11,W2.w)
        GW(12,W3.x) GW(13,W3.y) GW(14,W3.z) GW(15,W3.w)
        GW(16,W4.x) GW(17,W4.y) GW(18,W4.z) GW(19,W4.w)
        GW(20,W5.x) GW(21,W5.y) GW(22,W5.z) GW(23,W5.w)
        GW(24,W6.x) GW(25,W6.y) GW(26,W6.z) GW(27,W6.w)
        GW(28,W7.x) GW(29,W7.y) GW(30,W7.z) GW(31,W7.w)
#undef GW
    };
    // 16 -> 32 bit spread: bit d -> bit 2d
    auto spread16 = [](uint32_t x) {
        x = (x | (x << 8)) & 0x00FF00FFu;
        x = (x | (x << 4)) & 0x0F0F0F0Fu;
        x = (x | (x << 2)) & 0x33333333u;
        x = (x | (x << 1)) & 0x55555555u;
        return x;
    };

    float v0 = 0, v1 = 0, s0 = 0, s1 = 0;
    float c0, c1;
    load_idx(b);                         // idx(0)
    gather(c0, c1);                      // currents for t=0
    load_idx(BATCH + b);                 // idx(1)

    uint2* zp = (uint2*)(zmask + (size_t)b * 32 + (tile << 1));
    const int zstride = (BATCH * 32) >> 1;        // in uint2

    for (int t = 0; t < T_STEPS; ++t) {
        // combine parity halves (commutative add -> both lanes get identical c)
        c0 += __shfl_xor(c0, 32);
        c1 += __shfl_xor(c1, 32);

        float n0, n1;
        gather(n0, n1);                  // software-pipelined gather for t+1

        int rn = t + 2; if (rn > T_STEPS - 1) rn = T_STEPS - 1;
        load_idx(rn * BATCH + b);        // prefetch idx(t+2)

        // LIF (fma forms locked to round-1/3's passing arithmetic)
        s0 = __builtin_fmaf(s0, 0.875f, c0);
        s1 = __builtin_fmaf(s1, 0.875f, c1);
        v0 = __builtin_fmaf(0.125f, s0 - v0, v0);
        v1 = __builtin_fmaf(0.125f, s1 - v1, v1);

        unsigned long long m0 = __ballot(v0 > 1.0f);   // bit d (low32) -> h=2d
        unsigned long long m1 = __ballot(v1 > 1.0f);   // bit d (low32) -> h=2d+1
        if (v0 > 1.0f) v0 = 0.0f;
        if (v1 > 1.0f) v1 = 0.0f;

        // linear zmask: word w covers h = 32w..32w+31, bit j -> h = 32w+j
        uint32_t x0 = (uint32_t)m0, x1 = (uint32_t)m1;
        uint32_t wd0 = spread16(x0 & 0xFFFFu) | (spread16(x1 & 0xFFFFu) << 1);
        uint32_t wd1 = spread16(x0 >> 16)     | (spread16(x1 >> 16) << 1);
        if (l == 0) *zp = make_uint2(wd0, wd1);
        zp += zstride;
        c0 = n0; c1 = n1;
    }
}

// ---------------- Kernel 34: sparse output synapse + LI scan ----------------
// Grid: 128 b * 2 h-halves, 512 thr. Lane = (o, ch): o = tid>>4, ch = tid&15
// scans one zmask u32 word per t (linear bit->h mapping now). LI is linear ->
// per-lane partial LI; 3-level shfl tree + atomicAdds (deterministic).
__global__ __launch_bounds__(512) void k_li(const uint32_t* __restrict__ zmask,
                                            const float* __restrict__ w_o,
                                            float* __restrict__ out) {
    extern __shared__ __align__(16) float wo[];   // 32 * 521 floats = 66,688 B
    const int b = blockIdx.x >> 1, half = blockIdx.x & 1;
    const int tid = threadIdx.x;
    for (int lin = tid; lin < 32 * 512; lin += 512) {
        int o = lin >> 9, idx = lin & 511;
        wo[o * 521 + idx] = w_o[(size_t)o * N_H + half * 512 + idx];   // linear
    }
    __syncthreads();

    const int o = tid >> 4, ch = tid & 15;
    const float* wrow = wo + o * 521 + (ch << 5);
    const int woff = half * 16 + ch;

    float v = 0.0f, s = 0.0f;
    uint32_t m_n = zmask[(size_t)b * 32 + woff];
    for (int t = 0; t < T_STEPS; ++t) {
        uint32_t m = m_n;
        int tn = (t + 1 < T_STEPS) ? t + 1 : t;
        m_n = zmask[(size_t)(tn * BATCH + b) * 32 + woff];

        float c = 0.0f;
        while (m) { int j = __builtin_ctz(m); m &= m - 1; c += wrow[j]; }

        s = __builtin_fmaf(s, 0.875f, c);
        v = __builtin_fmaf(0.125f, s - v, v);

        float r = v + __shfl_xor(v, 1);
        r += __shfl_xor(r, 2);
        r += __shfl_xor(r, 4);
        if ((ch & 7) == 0)
            atomicAdd(out + (size_t)(t * BATCH + b) * 32 + o, r);
    }
}

// ---------------- launch ----------------
extern "C" void kernel_launch(void* const* d_in, const int* in_sizes, int n_in,
                              void* d_out, int out_size, void* d_ws, size_t ws_size,
                              hipStream_t stream) {
    const float* spikes = (const float*)d_in[0];
    const float* w_h    = (const float*)d_in[1];
    const float* w_o    = (const float*)d_in[2];
    float* out = (float*)d_out;

    char* ws = (char*)d_ws;
    uint32_t* pairs = (uint32_t*)(ws);                 // 8,388,608 B
    uint32_t* cnts  = (uint32_t*)(ws + 8388608);       //   262,144 B
    float*    w_t   = (float*)   (ws + 8650752);       // 1,048,576 B
    uint32_t* zmask = (uint32_t*)(ws + 9699328);       // 8,388,608 B

    const int lds12 = 257 * 64 * 4;    // 65,792 B -> 2 blocks/CU
    const int lds34 = 32 * 521 * 4;    // 66,688 B
    hipFuncSetAttribute((const void*)k_lif, hipFuncAttributeMaxDynamicSharedMemorySize, lds12);
    hipFuncSetAttribute((const void*)k_li,  hipFuncAttributeMaxDynamicSharedMemorySize, lds34);

    hipMemsetAsync(d_out, 0, (size_t)out_size * sizeof(float), stream);
    k_prep<<<(T_STEPS * BATCH) / 16, 256, 0, stream>>>(spikes, pairs, cnts);
    k_tr<<<(N_H * N_IN) / 256, 256, 0, stream>>>(w_h, w_t);
    k_lif<<<512, 256, lds12, stream>>>(pairs, cnts, w_t, zmask);
    k_li<<<BATCH * 2, 512, lds34, stream>>>(zmask, w_o, out);
}